// Round 12
// baseline (13856.430 us; speedup 1.0000x reference)
//
#include <hip/hip_runtime.h>
#include <stdint.h>

#ifndef THREEFRY_PARTITIONABLE
#define THREEFRY_PARTITIONABLE 1
#endif

#define LSEQ 128
#define BSZ  256
#define HD   512
#define G4   2048   // 4*HD

#define SEL_OFF  ((size_t)LSEQ * BSZ * LSEQ)            // 4194304
#define HY_OFF   (SEL_OFF + (size_t)LSEQ * BSZ)         // 4227072
#define CY_OFF   (HY_OFF + (size_t)BSZ * HD)            // 4358144

// ---------------- Threefry-2x32 (bit-exact vs JAX) ----------------
__device__ __forceinline__ uint32_t rotl_(uint32_t v, int r) { return (v << r) | (v >> (32 - r)); }

__device__ __forceinline__ void tf2x32(uint32_t k0, uint32_t k1,
                                       uint32_t x0, uint32_t x1,
                                       uint32_t &o0, uint32_t &o1)
{
  uint32_t k2 = k0 ^ k1 ^ 0x1BD11BDAu;
  x0 += k0; x1 += k1;
#define TFR(r) { x0 += x1; x1 = rotl_(x1,(r)); x1 ^= x0; }
  TFR(13) TFR(15) TFR(26) TFR(6)
  x0 += k1; x1 += k2 + 1u;
  TFR(17) TFR(29) TFR(16) TFR(24)
  x0 += k2; x1 += k0 + 2u;
  TFR(13) TFR(15) TFR(26) TFR(6)
  x0 += k0; x1 += k1 + 3u;
  TFR(17) TFR(29) TFR(16) TFR(24)
  x0 += k1; x1 += k2 + 4u;
  TFR(13) TFR(15) TFR(26) TFR(6)
  x0 += k2; x1 += k0 + 5u;
#undef TFR
  o0 = x0; o1 = x1;
}

__device__ __forceinline__ void step_key(int t, uint32_t &kA, uint32_t &kB)
{
#if THREEFRY_PARTITIONABLE
  uint32_t o0, o1;
  tf2x32(0u, 1u, 0u, (uint32_t)t, o0, o1);
  kA = o0; kB = o1;
#else
  uint32_t o0, o1;
  uint32_t j = 2u * (uint32_t)t;
  if (j < 127u) { tf2x32(0u, 1u, j, 127u + j, o0, o1); kA = o0; }
  else          { tf2x32(0u, 1u, j - 127u, j, o0, o1); kA = o1; }
  j = 2u * (uint32_t)t + 1u;
  if (j < 127u) { tf2x32(0u, 1u, j, 127u + j, o0, o1); kB = o0; }
  else          { tf2x32(0u, 1u, j - 127u, j, o0, o1); kB = o1; }
#endif
}

__device__ __forceinline__ uint32_t draw_bits(uint32_t kA, uint32_t kB, uint32_t n)
{
  uint32_t y0, y1;
#if THREEFRY_PARTITIONABLE
  tf2x32(kA, kB, 0u, n, y0, y1);
  return y0 ^ y1;
#else
  uint32_t i0 = (n < 16384u) ? n : n - 16384u;
  tf2x32(kA, kB, i0, i0 + 16384u, y0, y1);
  return (n < 16384u) ? y0 : y1;
#endif
}

// ---------------- fast f32 tanh (branch-free, ~1e-7 abs) ----------------
__device__ __forceinline__ float tanh_f(float xf)
{
  float ax = fabsf(xf);
  float z  = fminf(ax * 2.8853900817779268f, 50.0f);  // 2*log2(e), clamp
  float e  = __builtin_amdgcn_exp2f(z);
  float d  = e + 1.0f;
  float r0 = __builtin_amdgcn_rcpf(d);
  float r  = fmaf(fmaf(-d, r0, 1.0f), r0, r0);        // Newton: r ~= 1/d
  return copysignf(fmaf(-2.0f, r, 1.0f), xf);         // tanh(|x|) = 1 - 2/(e+1)
}

// ---------------- f32-input GEMM, chunked-f64 accumulate ----------------
// Double-buffered LDS: ONE barrier per K-tile. Per-output fmaf/promote order
// bit-identical to R11.
template<int CHUNK>
__global__ __launch_bounds__(512)
void gemm32(const float* __restrict__ A0, const float* __restrict__ A1, int lda,
            const float* __restrict__ B0, const float* __restrict__ B1, int ldb,
            const float* __restrict__ bias,
            double* __restrict__ Cd0, double* __restrict__ Cd1,
            float* __restrict__ Cf0, float* __restrict__ Cf1,
            int N, int K, int out_mode)
{
  constexpr int BM = 64;
  constexpr int BN = 64;
  constexpr int BK = 32;
  __shared__ float As[2][BK][BM];
  __shared__ float Bs[2][BK][BN];
  const int tid = threadIdx.x;
  const int tx = tid & 31, ty = tid >> 5;   // 32 cols-of-2, 16 rows-of-4
  const int z = blockIdx.z;
  const float* A = z ? A1 : A0;
  const float* B = z ? B1 : B0;
  const int m0 = blockIdx.x * BM;
  const int n0 = blockIdx.y * BN;

  const int r_ = tid >> 3, kq = (tid & 7) * 4;

  double acc[4][2];
  float  c32[4][2];
#pragma unroll
  for (int i = 0; i < 4; ++i)
#pragma unroll
    for (int j = 0; j < 2; ++j) { acc[i][j] = 0.0; c32[i][j] = 0.0f; }

  // prologue: stage tile 0 into buf 0
  {
    float4 w0 = *(const float4*)(B + (size_t)(n0 + r_) * ldb + kq);
    float4 u0 = *(const float4*)(A + (size_t)(m0 + r_) * lda + kq);
    Bs[0][kq + 0][r_] = w0.x; Bs[0][kq + 1][r_] = w0.y;
    Bs[0][kq + 2][r_] = w0.z; Bs[0][kq + 3][r_] = w0.w;
    As[0][kq + 0][r_] = u0.x; As[0][kq + 1][r_] = u0.y;
    As[0][kq + 2][r_] = u0.z; As[0][kq + 3][r_] = u0.w;
  }
  __syncthreads();

  const int NT = K / BK;
  for (int t = 0; t < NT; ++t) {
    const int cur = t & 1;
    float4 nw, nu;
    const bool more = (t + 1 < NT);
    if (more) {
      nw = *(const float4*)(B + (size_t)(n0 + r_) * ldb + (t + 1) * BK + kq);
      nu = *(const float4*)(A + (size_t)(m0 + r_) * lda + (t + 1) * BK + kq);
    }

#pragma unroll
    for (int kk = 0; kk < BK; ++kk) {
      float4 av = *(const float4*)&As[cur][kk][4 * ty];
      float2 bv = *(const float2*)&Bs[cur][kk][2 * tx];
      float a[4] = { av.x, av.y, av.z, av.w };
#pragma unroll
      for (int i = 0; i < 4; ++i) {
        c32[i][0] = fmaf(a[i], bv.x, c32[i][0]);
        c32[i][1] = fmaf(a[i], bv.y, c32[i][1]);
      }
      if ((kk & (CHUNK - 1)) == (CHUNK - 1)) {
#pragma unroll
        for (int i = 0; i < 4; ++i)
#pragma unroll
          for (int j = 0; j < 2; ++j) { acc[i][j] += (double)c32[i][j]; c32[i][j] = 0.0f; }
      }
    }

    if (more) {
      const int nxt = cur ^ 1;
      Bs[nxt][kq + 0][r_] = nw.x; Bs[nxt][kq + 1][r_] = nw.y;
      Bs[nxt][kq + 2][r_] = nw.z; Bs[nxt][kq + 3][r_] = nw.w;
      As[nxt][kq + 0][r_] = nu.x; As[nxt][kq + 1][r_] = nu.y;
      As[nxt][kq + 2][r_] = nu.z; As[nxt][kq + 3][r_] = nu.w;
    }
    __syncthreads();
  }

#pragma unroll
  for (int i = 0; i < 4; ++i) {
    int m = m0 + 4 * ty + i;
#pragma unroll
    for (int j = 0; j < 2; ++j) {
      int n = n0 + 2 * tx + j;
      double v = acc[i][j] + (bias ? (double)bias[n] : 0.0);
      if (out_mode == 0) {
        double* Cd = z ? Cd1 : Cd0;
        Cd[(size_t)m * N + n] = v;
      } else if (out_mode == 1) {
        Cf0[(((size_t)(m & 255)) * LSEQ + (m >> 8)) * HD + n] = (float)v;
      } else if (out_mode == 2) {
        Cf0[(size_t)m * N + n] = (float)v;
      } else if (out_mode == 3) {
        Cf0[(((size_t)(m & 255)) * HD + n) * LSEQ + (m >> 8)] = (float)v;
      } else {
        float* Cf = z ? Cf1 : Cf0;
        Cf[(size_t)m * N + n] = (float)v;
      }
    }
  }
}

// ---------------- 512x512 transpose ----------------
__global__ __launch_bounds__(256)
void transpose512(const float* __restrict__ W, float* __restrict__ WT)
{
  __shared__ float tile[32][33];
  int bx = blockIdx.x * 32, by = blockIdx.y * 32;
  int x = threadIdx.x & 31, y = threadIdx.x >> 5;   // 32 x 8
#pragma unroll
  for (int j = 0; j < 32; j += 8)
    tile[y + j][x] = W[(size_t)(by + y + j) * HD + bx + x];
  __syncthreads();
#pragma unroll
  for (int j = 0; j < 32; j += 8)
    WT[(size_t)(bx + y + j) * HD + by + x] = tile[x][y + j];
}

// score-phase per-element compute: pure-f32 tanh, f64 accumulate
#define SCOMP(A0_, A1_, A2_, A3_, V4, IT)                         \
  {                                                               \
    const int h_ = (IT) * 16 + hh;                                \
    const float  xq_ = (float)qs[h_];                             \
    const double vv_ = (double)vs[h_];                            \
    A0_ += vv_ * (double)tanh_f(xq_ + (V4).x);                    \
    A1_ += vv_ * (double)tanh_f(xq_ + (V4).y);                    \
    A2_ += vv_ * (double)tanh_f(xq_ + (V4).z);                    \
    A3_ += vv_ * (double)tanh_f(xq_ + (V4).w);                    \
  }

// ---------------- fused step, 512 threads ----------------
// R11 structure + single-wave softmax/sampling, deeper g_l batching,
// earlier e_p prefetch.
__global__ __launch_bounds__(512)
void step_fused(const float* __restrict__ g0, const float* __restrict__ g1,
                const float* __restrict__ bi, const float* __restrict__ bh,
                const double* __restrict__ c_in, double* __restrict__ c_out,
                float* __restrict__ h_out,
                const float* __restrict__ WqT, const float* __restrict__ g_bq,
                const float* __restrict__ e_g,
                const float* __restrict__ pWqT, const float* __restrict__ p_bq,
                const float* __restrict__ e_p,
                const float* __restrict__ g_v, const float* __restrict__ p_v,
                unsigned char* __restrict__ mask,
                const float* __restrict__ emb, float* __restrict__ dec_in,
                float* __restrict__ out, int t)
{
  const int b   = blockIdx.x;
  const int tid = threadIdx.x;
  const int lg  = tid & 31;          // l-group: owns l = 4*lg .. 4*lg+3
  const int hh  = tid >> 5;          // 0..15   (h residue class)
  __shared__ float  hs[HD];
  __shared__ double qs[HD];          // q1, then q2
  __shared__ float  vs[HD];          // g_v, then p_v
  __shared__ double part[16][LSEQ];  // per-hh partials
  __shared__ double gls[HD];         // g_l (f64)
  __shared__ double sarr[LSEQ];
  __shared__ int    selidx;

  const float* egbase = e_g + (size_t)b * (HD * LSEQ) + hh * LSEQ + lg * 4;
  const float* epbase = e_p + (size_t)b * (HD * LSEQ) + hh * LSEQ + lg * 4;

  // early prefetch: glimpse batch 0 (latency hides under LSTM)
  float4 B0[8], B1[8];
#pragma unroll
  for (int j = 0; j < 8; ++j)
    B0[j] = *(const float4*)(egbase + (size_t)j * (16 * LSEQ));

  // ---- LSTM pointwise, u = tid (identical f64 math) ----
  {
    const int u = tid;
    const size_t base = (size_t)b * G4;
    double gi = (double)g0[base + u]        + (double)g1[base + u]        + (double)bi[u]        + (double)bh[u];
    double gf = (double)g0[base + u + 512]  + (double)g1[base + u + 512]  + (double)bi[u + 512]  + (double)bh[u + 512];
    double gg = (double)g0[base + u + 1024] + (double)g1[base + u + 1024] + (double)bi[u + 1024] + (double)bh[u + 1024];
    double go = (double)g0[base + u + 1536] + (double)g1[base + u + 1536] + (double)bi[u + 1536] + (double)bh[u + 1536];
    double si = 1.0 / (1.0 + exp(-gi));
    double sf = 1.0 / (1.0 + exp(-gf));
    double so = 1.0 / (1.0 + exp(-go));
    double cy = sf * c_in[(size_t)b * HD + u] + si * tanh(gg);
    double hy = so * tanh(cy);
    c_out[(size_t)b * HD + u] = cy;
    float hyf = (float)hy;
    h_out[(size_t)b * HD + u] = hyf;
    hs[u] = hyf;
  }
  __syncthreads();

  // ---- q1[h] = sum_k hs[k]*WqT[k][h], chunks of 8 -> f64, 32-deep batching ----
  {
    const int h = tid;
    const float* wcol = WqT + h;
    float wA[32], wB[32];
    double a = 0.0;
#pragma unroll
    for (int j = 0; j < 32; ++j) wA[j] = wcol[(size_t)j * HD];
#pragma unroll
    for (int pair = 0; pair < 8; ++pair) {
      const int kA = pair * 64;
#pragma unroll
      for (int j = 0; j < 32; ++j) wB[j] = wcol[(size_t)(kA + 32 + j) * HD];
#pragma unroll
      for (int c = 0; c < 4; ++c) {
        float c32 = 0.0f;
#pragma unroll
        for (int j = 0; j < 8; ++j)
          c32 = fmaf(hs[kA + c * 8 + j], wA[c * 8 + j], c32);
        a += (double)c32;
      }
      if (pair < 7) {
#pragma unroll
        for (int j = 0; j < 32; ++j) wA[j] = wcol[(size_t)(kA + 64 + j) * HD];
      }
#pragma unroll
      for (int c = 0; c < 4; ++c) {
        float c32 = 0.0f;
#pragma unroll
        for (int j = 0; j < 8; ++j)
          c32 = fmaf(hs[kA + 32 + c * 8 + j], wB[c * 8 + j], c32);
        a += (double)c32;
      }
    }
    qs[tid] = a + (double)g_bq[tid];
    vs[tid] = g_v[tid];
  }
  __syncthreads();

  // ---- glimpse scores: ping-pong 8-batches ----
  {
    double a0 = 0, a1 = 0, a2 = 0, a3 = 0;
#pragma unroll
    for (int j = 0; j < 8; ++j)
      B1[j] = *(const float4*)(egbase + (size_t)(8 + j) * (16 * LSEQ));
#pragma unroll
    for (int j = 0; j < 8; ++j) SCOMP(a0, a1, a2, a3, B0[j], j);
#pragma unroll
    for (int j = 0; j < 8; ++j)
      B0[j] = *(const float4*)(egbase + (size_t)(16 + j) * (16 * LSEQ));
#pragma unroll
    for (int j = 0; j < 8; ++j) SCOMP(a0, a1, a2, a3, B1[j], 8 + j);
#pragma unroll
    for (int j = 0; j < 8; ++j)
      B1[j] = *(const float4*)(egbase + (size_t)(24 + j) * (16 * LSEQ));
#pragma unroll
    for (int j = 0; j < 8; ++j) SCOMP(a0, a1, a2, a3, B0[j], 16 + j);
#pragma unroll
    for (int j = 0; j < 8; ++j) SCOMP(a0, a1, a2, a3, B1[j], 24 + j);
    part[hh][lg * 4 + 0] = a0;
    part[hh][lg * 4 + 1] = a1;
    part[hh][lg * 4 + 2] = a2;
    part[hh][lg * 4 + 3] = a3;
  }

  // issue e_p batch 0 NOW (in flight across softmax + g_l + q2)
#pragma unroll
  for (int j = 0; j < 8; ++j)
    B0[j] = *(const float4*)(epbase + (size_t)j * (16 * LSEQ));
  __syncthreads();

  // ---- glimpse softmax: single wave, lane handles l=tid and l=tid+64 ----
  bool msk0 = false, msk1 = false;
  if (tid < 64) {
    msk0 = mask[(size_t)b * LSEQ + tid] != 0;
    msk1 = mask[(size_t)b * LSEQ + tid + 64] != 0;
    double u0 = 0.0, u1 = 0.0;
#pragma unroll
    for (int o = 0; o < 16; ++o) { u0 += part[o][tid]; u1 += part[o][tid + 64]; }
    if (msk0) u0 = -__builtin_inf();
    if (msk1) u1 = -__builtin_inf();
    double mx = fmax(u0, u1);
    for (int off = 32; off; off >>= 1) mx = fmax(mx, __shfl_xor(mx, off));
    double pe0 = msk0 ? 0.0 : exp(u0 - mx);
    double pe1 = msk1 ? 0.0 : exp(u1 - mx);
    double sm = pe0 + pe1;
    for (int off = 32; off; off >>= 1) sm += __shfl_xor(sm, off);
    sarr[tid]      = pe0 / sm;
    sarr[tid + 64] = pe1 / sm;
  }
  __syncthreads();

  // ---- g_l[h] = sum_l e_g[b][h][l]*s[l]  (contiguous rows, f64; 8-deep ping-pong) ----
  {
    const float4* row = (const float4*)(e_g + ((size_t)b * HD + tid) * LSEQ);
    float4 rA[8], rB[8];
    double a = 0.0;
#pragma unroll
    for (int j = 0; j < 8; ++j) rA[j] = row[j];
#pragma unroll
    for (int r = 0; r < 2; ++r) {
#pragma unroll
      for (int j = 0; j < 8; ++j) rB[j] = row[r * 16 + 8 + j];
#pragma unroll
      for (int j = 0; j < 8; ++j) {
        int l4 = (r * 16 + j) * 4;
        float4 v = rA[j];
        a += (double)v.x * sarr[l4 + 0];
        a += (double)v.y * sarr[l4 + 1];
        a += (double)v.z * sarr[l4 + 2];
        a += (double)v.w * sarr[l4 + 3];
      }
      if (r < 1) {
#pragma unroll
        for (int j = 0; j < 8; ++j) rA[j] = row[r * 16 + 16 + j];
      }
#pragma unroll
      for (int j = 0; j < 8; ++j) {
        int l4 = (r * 16 + 8 + j) * 4;
        float4 v = rB[j];
        a += (double)v.x * sarr[l4 + 0];
        a += (double)v.y * sarr[l4 + 1];
        a += (double)v.z * sarr[l4 + 2];
        a += (double)v.w * sarr[l4 + 3];
      }
    }
    gls[tid] = a;
  }
  __syncthreads();

  // ---- q2[h2] = sum_h gls[h]*pWqT[h][h2] + p_bq  (full f64; 32-deep batching) ----
  {
    const float* wcol = pWqT + tid;
    float wA[32], wB[32];
    double a = 0.0;
#pragma unroll
    for (int j = 0; j < 32; ++j) wA[j] = wcol[(size_t)j * HD];
#pragma unroll
    for (int pair = 0; pair < 8; ++pair) {
      const int hA = pair * 64;
#pragma unroll
      for (int j = 0; j < 32; ++j) wB[j] = wcol[(size_t)(hA + 32 + j) * HD];
#pragma unroll
      for (int j = 0; j < 32; ++j) a += gls[hA + j] * (double)wA[j];
      if (pair < 7) {
#pragma unroll
        for (int j = 0; j < 32; ++j) wA[j] = wcol[(size_t)(hA + 64 + j) * HD];
      }
#pragma unroll
      for (int j = 0; j < 32; ++j) a += gls[hA + 32 + j] * (double)wB[j];
    }
    qs[tid] = a + (double)p_bq[tid];
    vs[tid] = p_v[tid];
  }
  __syncthreads();

  // ---- pointer scores: same ping-pong on e_p (B0 already in flight) ----
  {
    double a0 = 0, a1 = 0, a2 = 0, a3 = 0;
#pragma unroll
    for (int j = 0; j < 8; ++j)
      B1[j] = *(const float4*)(epbase + (size_t)(8 + j) * (16 * LSEQ));
#pragma unroll
    for (int j = 0; j < 8; ++j) SCOMP(a0, a1, a2, a3, B0[j], j);
#pragma unroll
    for (int j = 0; j < 8; ++j)
      B0[j] = *(const float4*)(epbase + (size_t)(16 + j) * (16 * LSEQ));
#pragma unroll
    for (int j = 0; j < 8; ++j) SCOMP(a0, a1, a2, a3, B1[j], 8 + j);
#pragma unroll
    for (int j = 0; j < 8; ++j)
      B1[j] = *(const float4*)(epbase + (size_t)(24 + j) * (16 * LSEQ));
#pragma unroll
    for (int j = 0; j < 8; ++j) SCOMP(a0, a1, a2, a3, B0[j], 16 + j);
#pragma unroll
    for (int j = 0; j < 8; ++j) SCOMP(a0, a1, a2, a3, B1[j], 24 + j);
    part[hh][lg * 4 + 0] = a0;
    part[hh][lg * 4 + 1] = a1;
    part[hh][lg * 4 + 2] = a2;
    part[hh][lg * 4 + 3] = a3;
  }
  __syncthreads();

  // ---- pointer softmax + probs + gumbel sample + argmax: single wave ----
  if (tid < 64) {
    double a20 = 0.0, a21 = 0.0;
#pragma unroll
    for (int o = 0; o < 16; ++o) { a20 += part[o][tid]; a21 += part[o][tid + 64]; }
    double lt0 = msk0 ? -__builtin_inf() : 10.0 * tanh(a20);   // C_EXPL = 10
    double lt1 = msk1 ? -__builtin_inf() : 10.0 * tanh(a21);
    double mx = fmax(lt0, lt1);
    for (int off = 32; off; off >>= 1) mx = fmax(mx, __shfl_xor(mx, off));
    double pq0 = msk0 ? 0.0 : exp(lt0 - mx);
    double pq1 = msk1 ? 0.0 : exp(lt1 - mx);
    double sm = pq0 + pq1;
    for (int off = 32; off; off >>= 1) sm += __shfl_xor(sm, off);
    size_t obase = (size_t)(t + 1) * BSZ * LSEQ + (size_t)b * LSEQ;
    out[obase + tid]      = (float)(pq0 / sm);
    out[obase + tid + 64] = (float)(pq1 / sm);

    // gumbel, bit-exact vs jax.random.categorical
    uint32_t kA, kB;
    step_key(t, kA, kB);
    const float TINY = 1.17549435e-38f;
    uint32_t bits0 = draw_bits(kA, kB, (uint32_t)(b * LSEQ + tid));
    uint32_t bits1 = draw_bits(kA, kB, (uint32_t)(b * LSEQ + tid + 64));
    float f0 = __uint_as_float((bits0 >> 9) | 0x3f800000u) - 1.0f;
    float f1 = __uint_as_float((bits1 >> 9) | 0x3f800000u) - 1.0f;
    float uu0 = fmaxf(f0 * (1.0f - TINY) + TINY, TINY);
    float uu1 = fmaxf(f1 * (1.0f - TINY) + TINY, TINY);
    float gm0 = -logf(-logf(uu0));
    float gm1 = -logf(-logf(uu1));
    double cand0 = msk0 ? -__builtin_inf() : (lt0 + (double)gm0);
    double cand1 = msk1 ? -__builtin_inf() : (lt1 + (double)gm1);

    double cand;
    int idx;
    if (cand1 > cand0) { cand = cand1; idx = tid + 64; }
    else               { cand = cand0; idx = tid; }          // tie -> lower idx
    for (int off = 32; off; off >>= 1) {
      double c2 = __shfl_xor(cand, off);
      int    i2 = __shfl_xor(idx, off);
      if (c2 > cand || (c2 == cand && i2 < idx)) { cand = c2; idx = i2; }
    }
    if (tid == 0) {
      selidx = idx;
      out[SEL_OFF + (size_t)(t + 1) * BSZ + b] = (float)idx;
      mask[(size_t)b * LSEQ + idx] = 1;
    }
  }
  __syncthreads();
  {
    int sidx = selidx;
    dec_in[(size_t)b * HD + tid] = emb[((size_t)sidx * BSZ + b) * HD + tid];
  }
}

// ---------------- init / finalize ----------------
__global__ __launch_bounds__(256)
void init_kernel(const float* __restrict__ dec0, const float* __restrict__ h0,
                 const float* __restrict__ c0, float* __restrict__ dec_in,
                 float* __restrict__ hf, double* __restrict__ c,
                 unsigned char* __restrict__ mask, float* __restrict__ out)
{
  int i = blockIdx.x * blockDim.x + threadIdx.x;
  if (i < BSZ * HD) { hf[i] = h0[i]; c[i] = (double)c0[i]; dec_in[i] = dec0[i]; }
  if (i < BSZ * LSEQ) {
    mask[i] = ((i & (LSEQ - 1)) == 0) ? 1 : 0;
    out[i] = ((i & (LSEQ - 1)) == 0) ? 1.0f : 0.0f;
  }
  if (i < BSZ) out[SEL_OFF + i] = 0.0f;
}

__global__ __launch_bounds__(256)
void finalize(const float* __restrict__ hf, const double* __restrict__ c,
              float* __restrict__ out)
{
  int i = blockIdx.x * blockDim.x + threadIdx.x;
  if (i < BSZ * HD) {
    out[HY_OFF + i] = hf[i];
    out[CY_OFF + i] = (float)c[i];
  }
}

// ---------------- host ----------------
extern "C" void kernel_launch(void* const* d_in, const int* in_sizes, int n_in,
                              void* d_out, int out_size, void* d_ws, size_t ws_size,
                              hipStream_t stream)
{
  (void)in_sizes; (void)n_in; (void)out_size; (void)ws_size;
  const float* dec0  = (const float*)d_in[0];
  const float* emb   = (const float*)d_in[1];
  const float* h0    = (const float*)d_in[2];
  const float* c0    = (const float*)d_in[3];
  const float* ctx   = (const float*)d_in[4];
  const float* Wi    = (const float*)d_in[5];
  const float* bi    = (const float*)d_in[6];
  const float* Wh    = (const float*)d_in[7];
  const float* bh    = (const float*)d_in[8];
  const float* gWq   = (const float*)d_in[9];
  const float* gbq   = (const float*)d_in[10];
  const float* gWref = (const float*)d_in[11];
  const float* gbref = (const float*)d_in[12];
  const float* gv    = (const float*)d_in[13];
  const float* pWq   = (const float*)d_in[14];
  const float* pbq   = (const float*)d_in[15];
  const float* pWref = (const float*)d_in[16];
  const float* pbref = (const float*)d_in[17];
  const float* pv    = (const float*)d_in[18];
  float* out = (float*)d_out;

  char* ws = (char*)d_ws;
  size_t off = 0;
  auto take = [&](size_t bytes) -> char* {
    char* p = ws + off;
    off += (bytes + 255) & ~(size_t)255;
    return p;
  };
  float*  e_g   = (float*) take((size_t)BSZ * LSEQ * HD * 4);   // [b][h][l]
  float*  e_p   = (float*) take((size_t)BSZ * LSEQ * HD * 4);   // [b][h][l]
  float*  g0f   = (float*) take((size_t)BSZ * G4 * 4);          // dec@Wi^T partial (f32)
  float*  g1f   = (float*) take((size_t)BSZ * G4 * 4);          // h@Wh^T partial (f32)
  double* cb0   = (double*)take((size_t)BSZ * HD * 8);
  double* cb1   = (double*)take((size_t)BSZ * HD * 8);
  float*  hf0   = (float*) take((size_t)BSZ * HD * 4);
  float*  hf1   = (float*) take((size_t)BSZ * HD * 4);
  float*  WqT   = (float*) take((size_t)HD * HD * 4);           // gWq^T
  float*  pWqT  = (float*) take((size_t)HD * HD * 4);           // pWq^T
  float*  decb  = (float*) take((size_t)BSZ * HD * 4);
  unsigned char* mask = (unsigned char*)take((size_t)BSZ * LSEQ);

  init_kernel<<<512, 256, 0, stream>>>(dec0, h0, c0, decb, hf0, cb0, mask, out);
  transpose512<<<dim3(16, 16), 256, 0, stream>>>(gWq, WqT);
  transpose512<<<dim3(16, 16), 256, 0, stream>>>(pWq, pWqT);

  // e_g / e_p -> [b][h][l] (mode 3)
  gemm32<8><<<dim3(BSZ * LSEQ / 64, HD / 64, 1), 512, 0, stream>>>(
      ctx, nullptr, HD, gWref, nullptr, HD, gbref,
      nullptr, nullptr, e_g, nullptr, HD, HD, 3);
  gemm32<8><<<dim3(BSZ * LSEQ / 64, HD / 64, 1), 512, 0, stream>>>(
      ctx, nullptr, HD, pWref, nullptr, HD, pbref,
      nullptr, nullptr, e_p, nullptr, HD, HD, 3);

  double* cb[2] = { cb0, cb1 };
  float*  hf[2] = { hf0, hf1 };
  for (int t = 0; t < LSEQ - 1; ++t) {
    int rs = t & 1, wsl = rs ^ 1;
    // K1: gates partials (f32 out): z=0: dec_in@Wi^T -> g0f ; z=1: h@Wh^T -> g1f
    gemm32<8><<<dim3(BSZ / 64, G4 / 64, 2), 512, 0, stream>>>(
        decb, hf[rs], HD, Wi, Wh, HD, nullptr,
        nullptr, nullptr, g0f, g1f, G4, HD, 4);
    // K2: LSTM + q1 + glimpse + g_l + q2(pWqT) + pointer + sample + gather
    step_fused<<<BSZ, 512, 0, stream>>>(g0f, g1f, bi, bh,
                                        cb[rs], cb[wsl], hf[wsl],
                                        WqT, gbq, e_g, pWqT, pbq, e_p, gv, pv,
                                        mask, emb, decb, out, t);
  }
  finalize<<<BSZ * HD / 256, 256, 0, stream>>>(hf[1], cb[1], out);
}